// Round 1
// baseline (843.726 us; speedup 1.0000x reference)
//
#include <hip/hip_runtime.h>

// Problem constants (match reference)
constexpr int Bb = 8;
constexpr int Nn = 8192;
constexpr int Mm = 2048;
constexpr int C1 = 128;
constexpr int C2 = 256;
constexpr int Hh = 256;
constexpr int K1 = C1 + C2;  // 384
constexpr int NT = 32;       // columns (points) per block in fused kernel
constexpr int KC = 8;        // K-chunk staged in LDS for weights

// ---------------- generic 32x32 LDS tile transpose ----------------
// src: (z, R, C) row-major  ->  dst: (z, C, R)
// grid: (C/32, R/32, z), block (32, 8). Exact divisibility assumed (holds for all uses).
__global__ __launch_bounds__(256) void transpose_k(const float* __restrict__ src,
                                                   float* __restrict__ dst,
                                                   int R, int C) {
  __shared__ float tile[32][33];
  size_t off = (size_t)blockIdx.z * R * C;
  src += off;
  dst += off;
  int c0 = blockIdx.x * 32, r0 = blockIdx.y * 32;
  int tx = threadIdx.x, ty = threadIdx.y;
#pragma unroll
  for (int rr = ty; rr < 32; rr += 8)
    tile[rr][tx] = src[(size_t)(r0 + rr) * C + c0 + tx];
  __syncthreads();
#pragma unroll
  for (int cc = ty; cc < 32; cc += 8)
    dst[(size_t)(c0 + cc) * R + r0 + tx] = tile[tx][cc];
}

// ---------------- three_nn + weights ----------------
// One thread per unknown point; known points for the batch staged in LDS (SoA).
// grid: B*N/256 blocks of 256.
__global__ __launch_bounds__(256) void three_nn_k(const float* __restrict__ unknown,
                                                  const float* __restrict__ known,
                                                  int* __restrict__ idx3,
                                                  float* __restrict__ w3) {
  __shared__ float kx[Mm], ky[Mm], kz[Mm];
  int b = blockIdx.x >> 5;  // 8192/256 = 32 blocks per batch
  int n = ((blockIdx.x & 31) << 8) + threadIdx.x;
  const float* kb = known + (size_t)b * Mm * 3;
  for (int p = threadIdx.x; p < Mm; p += 256) {
    kx[p] = kb[3 * p];
    ky[p] = kb[3 * p + 1];
    kz[p] = kb[3 * p + 2];
  }
  __syncthreads();

  size_t ui = ((size_t)b * Nn + n) * 3;
  float ux = unknown[ui], uy = unknown[ui + 1], uz = unknown[ui + 2];

  float d0 = 1e30f, d1 = 1e30f, d2 = 1e30f;
  int i0 = 0, i1 = 0, i2 = 0;
#pragma unroll 4
  for (int jm = 0; jm < Mm; ++jm) {
    float dx = ux - kx[jm], dy = uy - ky[jm], dz = uz - kz[jm];
    float dd = dx * dx + dy * dy + dz * dz;
    if (dd < d2) {  // insertion keeps earliest index on ties (matches stable top_k)
      if (dd < d1) {
        d2 = d1; i2 = i1;
        if (dd < d0) { d1 = d0; i1 = i0; d0 = dd; i0 = jm; }
        else         { d1 = dd; i1 = jm; }
      } else { d2 = dd; i2 = jm; }
    }
  }

  float s0 = sqrtf(d0), s1 = sqrtf(d1), s2 = sqrtf(d2);
  float r0 = 1.f / (s0 + 1e-8f), r1 = 1.f / (s1 + 1e-8f), r2 = 1.f / (s2 + 1e-8f);
  float rs = 1.f / (r0 + r1 + r2);
  idx3[ui] = i0; idx3[ui + 1] = i1; idx3[ui + 2] = i2;
  w3[ui] = r0 * rs; w3[ui + 1] = r1 * rs; w3[ui + 2] = r2 * rs;
}

// ---------------- fused gather + concat + MLP1 + MLP2 ----------------
// Block: 256 threads handles one batch b and NT=32 output columns.
// F tile (K1 x NT, padded to 33) in LDS; W chunks (KC x 256) staged in LDS;
// h tile kept in registers then re-staged into the F region for MLP2.
// LDS: 384*33*4 + 8*256*4 = 58,880 B -> 2 blocks/CU.
__global__ __launch_bounds__(256) void fused_mlp_k(
    const float* __restrict__ uf,   // (B, C1, N)
    const float* __restrict__ kfT,  // (B, M, C2) transposed known_feats
    const float* __restrict__ W1T,  // (K1, H)
    const float* __restrict__ b1,   // (H)
    const float* __restrict__ W2T,  // (H, H)
    const float* __restrict__ b2,   // (H)
    const int* __restrict__ idx3,   // (B, N, 3)
    const float* __restrict__ w3,   // (B, N, 3)
    float* __restrict__ out) {      // (B, H, N)
  __shared__ float Fs[K1 * (NT + 1)];  // [384][33]; rows 0..255 reused as hS[256][33]
  __shared__ float Wts[KC * 256];

  int bid = blockIdx.x;
  int b = bid >> 8;             // 8192/32 = 256 tiles per batch
  int n0 = (bid & 255) * NT;
  int tid = threadIdx.x;

  // ---- Phase A: build F = [interpolated(C2) ; unknow_feats(C1)]
  {
    const float* kfb = kfT + (size_t)b * Mm * C2;
    int c = tid;  // one channel per thread (C2 == 256 == blockDim)
#pragma unroll 4
    for (int col = 0; col < NT; ++col) {
      size_t o3 = ((size_t)b * Nn + n0 + col) * 3;
      int j0 = idx3[o3], j1 = idx3[o3 + 1], j2 = idx3[o3 + 2];
      float wa = w3[o3], wb = w3[o3 + 1], wc = w3[o3 + 2];
      // lanes c=0..255 -> 1KB contiguous reads per gathered row (L2-resident)
      Fs[c * (NT + 1) + col] = wa * kfb[(size_t)j0 * C2 + c] +
                               wb * kfb[(size_t)j1 * C2 + c] +
                               wc * kfb[(size_t)j2 * C2 + c];
    }
#pragma unroll
    for (int e = tid; e < C1 * NT; e += 256) {
      int c1 = e >> 5, col = e & (NT - 1);
      Fs[(C2 + c1) * (NT + 1) + col] = uf[((size_t)b * C1 + c1) * Nn + n0 + col];
    }
  }
  __syncthreads();

  int i = tid >> 3;  // row group: output rows i*8 .. i*8+7
  int j = tid & 7;   // col group: cols j*4 .. j*4+3

  float acc[8][4];
#pragma unroll
  for (int r = 0; r < 8; ++r)
#pragma unroll
    for (int q = 0; q < 4; ++q) acc[r][q] = 0.f;

  // ---- MLP1: h = relu(W1 @ F + b1), K = 384
  for (int kc = 0; kc < K1 / KC; ++kc) {
#pragma unroll
    for (int e = tid; e < KC * 256; e += 256)
      Wts[e] = W1T[(size_t)kc * KC * 256 + e];
    __syncthreads();
#pragma unroll
    for (int c = 0; c < KC; ++c) {
      float w[8], f[4];
#pragma unroll
      for (int r = 0; r < 8; ++r) w[r] = Wts[c * 256 + i * 8 + r];
#pragma unroll
      for (int q = 0; q < 4; ++q) f[q] = Fs[(kc * KC + c) * (NT + 1) + j * 4 + q];
#pragma unroll
      for (int r = 0; r < 8; ++r)
#pragma unroll
        for (int q = 0; q < 4; ++q) acc[r][q] += w[r] * f[q];
    }
    __syncthreads();
  }

  // ---- stash h (bias + relu) into Fs region as hS[256][33]
#pragma unroll
  for (int r = 0; r < 8; ++r) {
    float bv = b1[i * 8 + r];
#pragma unroll
    for (int q = 0; q < 4; ++q) {
      float v = acc[r][q] + bv;
      Fs[(i * 8 + r) * (NT + 1) + j * 4 + q] = v > 0.f ? v : 0.f;
      acc[r][q] = 0.f;
    }
  }
  __syncthreads();

  // ---- MLP2: out = relu(W2 @ h + b2), K = 256
  for (int kc = 0; kc < Hh / KC; ++kc) {
#pragma unroll
    for (int e = tid; e < KC * 256; e += 256)
      Wts[e] = W2T[(size_t)kc * KC * 256 + e];
    __syncthreads();
#pragma unroll
    for (int c = 0; c < KC; ++c) {
      float w[8], f[4];
#pragma unroll
      for (int r = 0; r < 8; ++r) w[r] = Wts[c * 256 + i * 8 + r];
#pragma unroll
      for (int q = 0; q < 4; ++q) f[q] = Fs[(kc * KC + c) * (NT + 1) + j * 4 + q];
#pragma unroll
      for (int r = 0; r < 8; ++r)
#pragma unroll
        for (int q = 0; q < 4; ++q) acc[r][q] += w[r] * f[q];
    }
    __syncthreads();
  }

  // ---- epilogue: bias + relu, float4 stores
#pragma unroll
  for (int r = 0; r < 8; ++r) {
    float bv = b2[i * 8 + r];
    float4 v;
    v.x = fmaxf(acc[r][0] + bv, 0.f);
    v.y = fmaxf(acc[r][1] + bv, 0.f);
    v.z = fmaxf(acc[r][2] + bv, 0.f);
    v.w = fmaxf(acc[r][3] + bv, 0.f);
    *(float4*)(&out[((size_t)b * Hh + i * 8 + r) * Nn + n0 + j * 4]) = v;
  }
}

extern "C" void kernel_launch(void* const* d_in, const int* in_sizes, int n_in,
                              void* d_out, int out_size, void* d_ws, size_t ws_size,
                              hipStream_t stream) {
  const float* unknown = (const float*)d_in[0];  // (8, 8192, 3)
  const float* known   = (const float*)d_in[1];  // (8, 2048, 3)
  const float* uf      = (const float*)d_in[2];  // (8, 128, 8192)
  const float* kf      = (const float*)d_in[3];  // (8, 256, 2048)
  const float* W1      = (const float*)d_in[4];  // (256, 384)
  const float* b1      = (const float*)d_in[5];  // (256)
  const float* W2      = (const float*)d_in[6];  // (256, 256)
  const float* b2      = (const float*)d_in[7];  // (256)
  float* out = (float*)d_out;                    // (8, 256, 8192)

  // workspace layout (floats), ~19 MB total
  float* ws  = (float*)d_ws;
  float* kfT = ws;                                // 8*2048*256
  float* W1T = kfT + (size_t)Bb * Mm * C2;        // 384*256
  float* W2T = W1T + (size_t)K1 * Hh;             // 256*256
  float* w3  = W2T + (size_t)Hh * Hh;             // 8*8192*3
  int* idx3  = (int*)(w3 + (size_t)Bb * Nn * 3);  // 8*8192*3

  // transposes: known_feats -> (B, M, C2); W1 -> (K1, H); W2 -> (H, H)
  transpose_k<<<dim3(Mm / 32, C2 / 32, Bb), dim3(32, 8), 0, stream>>>(kf, kfT, C2, Mm);
  transpose_k<<<dim3(K1 / 32, Hh / 32, 1), dim3(32, 8), 0, stream>>>(W1, W1T, Hh, K1);
  transpose_k<<<dim3(Hh / 32, Hh / 32, 1), dim3(32, 8), 0, stream>>>(W2, W2T, Hh, Hh);

  three_nn_k<<<dim3(Bb * Nn / 256), dim3(256), 0, stream>>>(unknown, known, idx3, w3);

  fused_mlp_k<<<dim3(Bb * (Nn / NT)), dim3(256), 0, stream>>>(
      uf, kfT, W1T, b1, W2T, b2, idx3, w3, out);
}

// Round 2
// 257.263 us; speedup vs baseline: 3.2796x; 3.2796x over previous
//
#include <hip/hip_runtime.h>

using bf16x8 = __attribute__((ext_vector_type(8))) short;
using f32x4  = __attribute__((ext_vector_type(4))) float;

constexpr int Bb = 8, Nn = 8192, Mm = 2048, C1 = 128, C2 = 256, Hh = 256, K1 = 384;
constexpr int KT1 = K1 / 32;     // 12 k-tiles for GEMM1
constexpr int KT2 = Hh / 32;     // 8 k-tiles for GEMM2
constexpr int RT = Hh / 16;      // 16 row-tiles
constexpr int NTILES = Nn / 16;  // 512 col-tiles per batch

__device__ __forceinline__ short f2bf(float x) {  // RNE float->bf16
  union { float f; unsigned u; } v; v.f = x;
  unsigned r = v.u + 0x7fff + ((v.u >> 16) & 1);
  return (short)(r >> 16);
}

// ---------------- 32x32 tile transpose: (z,R,C) -> (z,C,R) ----------------
__global__ __launch_bounds__(256) void transpose_k(const float* __restrict__ src,
                                                   float* __restrict__ dst, int R, int C) {
  __shared__ float tile[32][33];
  size_t off = (size_t)blockIdx.z * R * C;
  src += off; dst += off;
  int c0 = blockIdx.x * 32, r0 = blockIdx.y * 32;
  int tx = threadIdx.x, ty = threadIdx.y;
#pragma unroll
  for (int rr = ty; rr < 32; rr += 8) tile[rr][tx] = src[(size_t)(r0 + rr) * C + c0 + tx];
  __syncthreads();
#pragma unroll
  for (int cc = ty; cc < 32; cc += 8) dst[(size_t)(c0 + cc) * R + r0 + tx] = tile[tx][cc];
}

// ------------- prep W1/W2 into bf16 A-fragment planes -------------
// A-frag layout (16x16x32): lane holds A[m=lane&15][k0..k0+7], k0=(lane>>4)*8.
// Plane index: ((kt*RT + rowtile)*64 + lane)*8 + j
__global__ __launch_bounds__(256) void prep_w_k(const float* __restrict__ W1,
                                                const float* __restrict__ W2,
                                                short* __restrict__ W1f,
                                                short* __restrict__ W2f) {
  int id = blockIdx.x * 256 + threadIdx.x;
  const int n1 = KT1 * RT * 64;
  const int n2 = KT2 * RT * 64;
  if (id < n1) {
    int lane = id & 63, tile = id >> 6;
    int kt = tile / RT, rt = tile % RT;
    int m = rt * 16 + (lane & 15), k0 = kt * 32 + (lane >> 4) * 8;
    bf16x8 f;
#pragma unroll
    for (int j = 0; j < 8; ++j) f[j] = f2bf(W1[(size_t)m * K1 + k0 + j]);
    *(bf16x8*)(W1f + (size_t)id * 8) = f;
  } else if (id < n1 + n2) {
    int id2 = id - n1;
    int lane = id2 & 63, tile = id2 >> 6;
    int kt = tile / RT, rt = tile % RT;
    int m = rt * 16 + (lane & 15), k0 = kt * 32 + (lane >> 4) * 8;
    bf16x8 f;
#pragma unroll
    for (int j = 0; j < 8; ++j) f[j] = f2bf(W2[(size_t)m * Hh + k0 + j]);
    *(bf16x8*)(W2f + (size_t)id2 * 8) = f;
  }
}

// ------------- three_nn over half the candidate set (branchless) -------------
// grid: b(8) x nblk(32) x half(2) = 512 blocks of 256
__global__ __launch_bounds__(256) void nn_half_k(const float* __restrict__ unknown,
                                                 const float* __restrict__ known,
                                                 float* __restrict__ pd,
                                                 int* __restrict__ pi) {
  __shared__ float kx[1024], ky[1024], kz[1024];
  int bid = blockIdx.x;
  int b = bid >> 6, rem = bid & 63;
  int half = rem & 1, nblk = rem >> 1;
  int n = nblk * 256 + threadIdx.x;
  const float* kb = known + ((size_t)b * Mm + half * 1024) * 3;
  for (int p = threadIdx.x; p < 1024; p += 256) {
    kx[p] = kb[3 * p]; ky[p] = kb[3 * p + 1]; kz[p] = kb[3 * p + 2];
  }
  __syncthreads();

  size_t ui = ((size_t)b * Nn + n) * 3;
  float ux = unknown[ui], uy = unknown[ui + 1], uz = unknown[ui + 2];
  float d0 = 1e30f, d1 = 1e30f, d2 = 1e30f;
  int i0 = 0, i1 = 0, i2 = 0;
  int gbase = half * 1024;

#define NN_STEP(xx, yy, zz, q)                                          \
  {                                                                     \
    float dx = ux - (xx), dy = uy - (yy), dz = uz - (zz);               \
    float dd = dx * dx + dy * dy + dz * dz;                             \
    int jm = gbase + jb + (q);                                          \
    bool c0 = dd < d0, c1 = dd < d1, c2 = dd < d2;                      \
    d2 = c1 ? d1 : (c2 ? dd : d2); i2 = c1 ? i1 : (c2 ? jm : i2);       \
    d1 = c0 ? d0 : (c1 ? dd : d1); i1 = c0 ? i0 : (c1 ? jm : i1);       \
    d0 = c0 ? dd : d0;             i0 = c0 ? jm : i0;                   \
  }

  for (int jb = 0; jb < 1024; jb += 4) {
    float4 xs = *(const float4*)&kx[jb];
    float4 ys = *(const float4*)&ky[jb];
    float4 zs = *(const float4*)&kz[jb];
    NN_STEP(xs.x, ys.x, zs.x, 0)
    NN_STEP(xs.y, ys.y, zs.y, 1)
    NN_STEP(xs.z, ys.z, zs.z, 2)
    NN_STEP(xs.w, ys.w, zs.w, 3)
  }
#undef NN_STEP

  size_t o = (((size_t)b * Nn + n) * 2 + half) * 3;
  pd[o] = d0; pd[o + 1] = d1; pd[o + 2] = d2;
  pi[o] = i0; pi[o + 1] = i1; pi[o + 2] = i2;
}

// ------------- merge the two sorted triples, compute weights -------------
__global__ __launch_bounds__(256) void nn_merge_k(const float* __restrict__ pd,
                                                  const int* __restrict__ pi,
                                                  int* __restrict__ idx3,
                                                  float* __restrict__ w3) {
  int t = blockIdx.x * 256 + threadIdx.x;  // flat b*N+n
  size_t o = (size_t)t * 6;
  float a0 = pd[o], a1 = pd[o + 1], a2 = pd[o + 2];
  float b0 = pd[o + 3], b1v = pd[o + 4], b2v = pd[o + 5];
  int A0 = pi[o], A1 = pi[o + 1], A2 = pi[o + 2];
  int B0 = pi[o + 3], B1 = pi[o + 4], B2 = pi[o + 5];
  // stable 2-list merge: ties prefer list a (lower global index)
  bool ta = a0 <= b0;
  float m0 = ta ? a0 : b0; int j0 = ta ? A0 : B0;
  float na0 = ta ? a1 : a0, na1 = ta ? a2 : a1;
  int   nA0 = ta ? A1 : A0, nA1 = ta ? A2 : A1;
  float nb0 = ta ? b0 : b1v, nb1 = ta ? b1v : b2v;
  int   nB0 = ta ? B0 : B1,  nB1 = ta ? B1 : B2;
  ta = na0 <= nb0;
  float m1 = ta ? na0 : nb0; int j1 = ta ? nA0 : nB0;
  float ma0 = ta ? na1 : na0; int mA0 = ta ? nA1 : nA0;
  float mb0 = ta ? nb0 : nb1; int mB0 = ta ? nB0 : nB1;
  ta = ma0 <= mb0;
  float m2 = ta ? ma0 : mb0; int j2 = ta ? mA0 : mB0;

  float s0 = sqrtf(m0), s1 = sqrtf(m1), s2 = sqrtf(m2);
  float r0 = 1.f / (s0 + 1e-8f), r1 = 1.f / (s1 + 1e-8f), r2 = 1.f / (s2 + 1e-8f);
  float rs = 1.f / (r0 + r1 + r2);
  size_t ui = (size_t)t * 3;
  idx3[ui] = j0; idx3[ui + 1] = j1; idx3[ui + 2] = j2;
  w3[ui] = r0 * rs; w3[ui + 1] = r1 * rs; w3[ui + 2] = r2 * rs;
}

// ------------- GEMM1: gather+concat F into LDS frags, h = relu(W1@F+b1) -------------
// block = 256 thr (4 waves), covers 64 cols x all 256 rows. grid = 8*128.
__global__ __launch_bounds__(256) void gemm1_k(const float* __restrict__ uf,
                                               const float* __restrict__ kfT,
                                               const short* __restrict__ W1f,
                                               const float* __restrict__ b1,
                                               const int* __restrict__ idx3,
                                               const float* __restrict__ w3,
                                               short* __restrict__ hfrag) {
  __shared__ short Fs[KT1 * 4 * 64 * 8];  // 49152 B, B-frag order [kt][ntl][lane][j]
  int bid = blockIdx.x;
  int b = bid >> 7, bt = bid & 127;  // n0 = bt*64
  int tid = threadIdx.x, lane = tid & 63, wv = tid >> 6;
  int quad = lane >> 4, col = lane & 15;

  // Phase A: build F-frags. thread = (ntl=wv, lane); loops all 12 k-tiles.
  {
    int n = bt * 64 + wv * 16 + col;
    size_t o3 = ((size_t)b * Nn + n) * 3;
    int g0 = idx3[o3], g1 = idx3[o3 + 1], g2 = idx3[o3 + 2];
    float w0 = w3[o3], w1 = w3[o3 + 1], w2 = w3[o3 + 2];
    const float* kfb = kfT + (size_t)b * Mm * C2;
#pragma unroll 2
    for (int kt = 0; kt < 8; ++kt) {  // interpolated region (C2 channels)
      int c0 = kt * 32 + quad * 8;
      float4 p0a = *(const float4*)&kfb[(size_t)g0 * C2 + c0];
      float4 p0b = *(const float4*)&kfb[(size_t)g0 * C2 + c0 + 4];
      float4 p1a = *(const float4*)&kfb[(size_t)g1 * C2 + c0];
      float4 p1b = *(const float4*)&kfb[(size_t)g1 * C2 + c0 + 4];
      float4 p2a = *(const float4*)&kfb[(size_t)g2 * C2 + c0];
      float4 p2b = *(const float4*)&kfb[(size_t)g2 * C2 + c0 + 4];
      bf16x8 f;
      f[0] = f2bf(w0 * p0a.x + w1 * p1a.x + w2 * p2a.x);
      f[1] = f2bf(w0 * p0a.y + w1 * p1a.y + w2 * p2a.y);
      f[2] = f2bf(w0 * p0a.z + w1 * p1a.z + w2 * p2a.z);
      f[3] = f2bf(w0 * p0a.w + w1 * p1a.w + w2 * p2a.w);
      f[4] = f2bf(w0 * p0b.x + w1 * p1b.x + w2 * p2b.x);
      f[5] = f2bf(w0 * p0b.y + w1 * p1b.y + w2 * p2b.y);
      f[6] = f2bf(w0 * p0b.z + w1 * p1b.z + w2 * p2b.z);
      f[7] = f2bf(w0 * p0b.w + w1 * p1b.w + w2 * p2b.w);
      *(bf16x8*)&Fs[((kt * 4 + wv) * 64 + lane) * 8] = f;
    }
#pragma unroll 2
    for (int kt = 8; kt < 12; ++kt) {  // unknow_feats region (C1 channels)
      int c1 = (kt - 8) * 32 + quad * 8;
      bf16x8 f;
#pragma unroll
      for (int j = 0; j < 8; ++j)
        f[j] = f2bf(uf[((size_t)b * C1 + c1 + j) * Nn + n]);
      *(bf16x8*)&Fs[((kt * 4 + wv) * 64 + lane) * 8] = f;
    }
  }
  __syncthreads();

  // Phase B: K-loop. wave wv owns rows wv*64..+63 (4 row-tiles) x 4 col-tiles.
  f32x4 acc[4][4];
#pragma unroll
  for (int r = 0; r < 4; ++r)
#pragma unroll
    for (int c = 0; c < 4; ++c) acc[r][c] = (f32x4){0.f, 0.f, 0.f, 0.f};

  for (int kt = 0; kt < KT1; ++kt) {
    bf16x8 Afr[4], Bfr[4];
#pragma unroll
    for (int r = 0; r < 4; ++r)
      Afr[r] = *(const bf16x8*)(W1f + ((size_t)(kt * RT + wv * 4 + r) * 64 + lane) * 8);
#pragma unroll
    for (int c = 0; c < 4; ++c)
      Bfr[c] = *(const bf16x8*)&Fs[((kt * 4 + c) * 64 + lane) * 8];
#pragma unroll
    for (int r = 0; r < 4; ++r)
#pragma unroll
      for (int c = 0; c < 4; ++c)
        acc[r][c] = __builtin_amdgcn_mfma_f32_16x16x32_bf16(Afr[r], Bfr[c], acc[r][c], 0, 0, 0);
  }
  __syncthreads();  // all waves done reading Fs; reuse as epilogue scratch

  // Epilogue: bias+relu, D-layout -> B-frag layout via per-wave 32x17 LDS scratch
  float* sc = (float*)Fs + wv * 544;
  for (int ktl = 0; ktl < 2; ++ktl) {
    for (int c = 0; c < 4; ++c) {
#pragma unroll
      for (int r2 = 0; r2 < 2; ++r2) {
        int r = ktl * 2 + r2;
#pragma unroll
        for (int reg = 0; reg < 4; ++reg) {
          int rowg = wv * 64 + r * 16 + quad * 4 + reg;
          float hv = fmaxf(acc[r][c][reg] + b1[rowg], 0.f);
          sc[(r2 * 16 + quad * 4 + reg) * 17 + col] = hv;
        }
      }
      __syncthreads();  // cross-lane LDS RAW
      bf16x8 f;
#pragma unroll
      for (int j = 0; j < 8; ++j) f[j] = f2bf(sc[(quad * 8 + j) * 17 + col]);
      int ktg = wv * 2 + ktl;
      int ntile = bt * 4 + c;
      *(bf16x8*)(hfrag + (((size_t)b * KT2 + ktg) * NTILES + ntile) * 64 * 8 + lane * 8) = f;
      __syncthreads();  // cross-lane LDS WAR before next iteration reuses scratch
    }
  }
}

// ------------- GEMM2: out = relu(W2@h+b2), frags straight from global -------------
__global__ __launch_bounds__(256) void gemm2_k(const short* __restrict__ W2f,
                                               const short* __restrict__ hfrag,
                                               const float* __restrict__ b2,
                                               float* __restrict__ out) {
  int bid = blockIdx.x;
  int b = bid >> 7, bt = bid & 127;
  int tid = threadIdx.x, lane = tid & 63, wv = tid >> 6;
  int quad = lane >> 4, col = lane & 15;

  f32x4 acc[4][4];
#pragma unroll
  for (int r = 0; r < 4; ++r)
#pragma unroll
    for (int c = 0; c < 4; ++c) acc[r][c] = (f32x4){0.f, 0.f, 0.f, 0.f};

  for (int kt = 0; kt < KT2; ++kt) {
    bf16x8 Afr[4], Bfr[4];
#pragma unroll
    for (int r = 0; r < 4; ++r)
      Afr[r] = *(const bf16x8*)(W2f + ((size_t)(kt * RT + wv * 4 + r) * 64 + lane) * 8);
#pragma unroll
    for (int c = 0; c < 4; ++c)
      Bfr[c] = *(const bf16x8*)(hfrag +
               (((size_t)b * KT2 + kt) * NTILES + bt * 4 + c) * 64 * 8 + lane * 8);
#pragma unroll
    for (int r = 0; r < 4; ++r)
#pragma unroll
      for (int c = 0; c < 4; ++c)
        acc[r][c] = __builtin_amdgcn_mfma_f32_16x16x32_bf16(Afr[r], Bfr[c], acc[r][c], 0, 0, 0);
  }

#pragma unroll
  for (int r = 0; r < 4; ++r)
#pragma unroll
    for (int c = 0; c < 4; ++c)
#pragma unroll
      for (int reg = 0; reg < 4; ++reg) {
        int rowg = wv * 64 + r * 16 + quad * 4 + reg;
        int n = bt * 64 + c * 16 + col;
        out[((size_t)b * Hh + rowg) * Nn + n] = fmaxf(acc[r][c][reg] + b2[rowg], 0.f);
      }
}

extern "C" void kernel_launch(void* const* d_in, const int* in_sizes, int n_in,
                              void* d_out, int out_size, void* d_ws, size_t ws_size,
                              hipStream_t stream) {
  const float* unknown = (const float*)d_in[0];
  const float* known   = (const float*)d_in[1];
  const float* uf      = (const float*)d_in[2];
  const float* kf      = (const float*)d_in[3];
  const float* W1      = (const float*)d_in[4];
  const float* b1      = (const float*)d_in[5];
  const float* W2      = (const float*)d_in[6];
  const float* b2      = (const float*)d_in[7];
  float* out = (float*)d_out;

  // ws layout (~53 MB)
  char* p = (char*)d_ws;
  float* kfT = (float*)p;  p += (size_t)Bb * Mm * C2 * 4;        // 16.8 MB
  int* idx3  = (int*)p;    p += (size_t)Bb * Nn * 3 * 4;         // 0.79 MB
  float* w3  = (float*)p;  p += (size_t)Bb * Nn * 3 * 4;         // 0.79 MB
  short* W1f = (short*)p;  p += (size_t)KT1 * RT * 64 * 8 * 2;   // 0.20 MB
  short* W2f = (short*)p;  p += (size_t)KT2 * RT * 64 * 8 * 2;   // 0.13 MB
  short* hfrag = (short*)p; p += (size_t)Bb * KT2 * NTILES * 64 * 8 * 2;  // 33.6 MB
  float* pd  = (float*)p;  p += (size_t)Bb * Nn * 2 * 3 * 4;     // 1.6 MB
  int* pi    = (int*)p;    p += (size_t)Bb * Nn * 2 * 3 * 4;     // 1.6 MB

  transpose_k<<<dim3(Mm / 32, C2 / 32, Bb), dim3(32, 8), 0, stream>>>(kf, kfT, C2, Mm);
  prep_w_k<<<dim3((KT1 * RT * 64 + KT2 * RT * 64) / 256), dim3(256), 0, stream>>>(W1, W2, W1f, W2f);
  nn_half_k<<<dim3(Bb * 64), dim3(256), 0, stream>>>(unknown, known, pd, pi);
  nn_merge_k<<<dim3(Bb * Nn / 256), dim3(256), 0, stream>>>(pd, pi, idx3, w3);
  gemm1_k<<<dim3(Bb * (Nn / 64)), dim3(256), 0, stream>>>(uf, kfT, W1f, b1, idx3, w3, hfrag);
  gemm2_k<<<dim3(Bb * (Nn / 64)), dim3(256), 0, stream>>>(W2f, hfrag, b2, out);
}

// Round 3
// 241.078 us; speedup vs baseline: 3.4998x; 1.0671x over previous
//
#include <hip/hip_runtime.h>

using bf16x8 = __attribute__((ext_vector_type(8))) short;
using f32x4  = __attribute__((ext_vector_type(4))) float;

constexpr int Bb = 8, Nn = 8192, Mm = 2048, C1 = 128, C2 = 256, Hh = 256, K1 = 384;
constexpr int KT1 = K1 / 32;   // 12 k-tiles for GEMM1
constexpr int KT2 = Hh / 32;   // 8 k-tiles for GEMM2
constexpr int RT = Hh / 16;    // 16 row-tiles

__device__ __forceinline__ short f2bf(float x) {  // RNE float->bf16
  union { float f; unsigned u; } v; v.f = x;
  unsigned r = v.u + 0x7fff + ((v.u >> 16) & 1);
  return (short)(r >> 16);
}

// ---------------- 32x32 tile transpose: (z,R,C) -> (z,C,R) ----------------
__global__ __launch_bounds__(256) void transpose_k(const float* __restrict__ src,
                                                   float* __restrict__ dst, int R, int C) {
  __shared__ float tile[32][33];
  size_t off = (size_t)blockIdx.z * R * C;
  src += off; dst += off;
  int c0 = blockIdx.x * 32, r0 = blockIdx.y * 32;
  int tx = threadIdx.x, ty = threadIdx.y;
#pragma unroll
  for (int rr = ty; rr < 32; rr += 8) tile[rr][tx] = src[(size_t)(r0 + rr) * C + c0 + tx];
  __syncthreads();
#pragma unroll
  for (int cc = ty; cc < 32; cc += 8) dst[(size_t)(c0 + cc) * R + r0 + tx] = tile[tx][cc];
}

// ------------- prep W1/W2 into bf16 A-fragment planes -------------
// A-frag (16x16x32): lane holds A[m=lane&15][k0..k0+7], k0=(lane>>4)*8.
__global__ __launch_bounds__(256) void prep_w_k(const float* __restrict__ W1,
                                                const float* __restrict__ W2,
                                                short* __restrict__ W1f,
                                                short* __restrict__ W2f) {
  int id = blockIdx.x * 256 + threadIdx.x;
  const int n1 = KT1 * RT * 64;
  const int n2 = KT2 * RT * 64;
  if (id < n1) {
    int lane = id & 63, tile = id >> 6;
    int kt = tile / RT, rt = tile % RT;
    int m = rt * 16 + (lane & 15), k0 = kt * 32 + (lane >> 4) * 8;
    bf16x8 f;
#pragma unroll
    for (int j = 0; j < 8; ++j) f[j] = f2bf(W1[(size_t)m * K1 + k0 + j]);
    *(bf16x8*)(W1f + (size_t)id * 8) = f;
  } else if (id < n1 + n2) {
    int id2 = id - n1;
    int lane = id2 & 63, tile = id2 >> 6;
    int kt = tile / RT, rt = tile % RT;
    int m = rt * 16 + (lane & 15), k0 = kt * 32 + (lane >> 4) * 8;
    bf16x8 f;
#pragma unroll
    for (int j = 0; j < 8; ++j) f[j] = f2bf(W2[(size_t)m * Hh + k0 + j]);
    *(bf16x8*)(W2f + (size_t)id2 * 8) = f;
  }
}

// ------------- three_nn over half the candidate set -------------
// Fast path: dist only + wave-uniform skip; insert chain only when some lane improves.
__global__ __launch_bounds__(256) void nn_half_k(const float* __restrict__ unknown,
                                                 const float* __restrict__ known,
                                                 float* __restrict__ pd,
                                                 int* __restrict__ pi) {
  __shared__ float kx[1024], ky[1024], kz[1024];
  int bid = blockIdx.x;
  int b = bid >> 6, rem = bid & 63;
  int half = rem & 1, nblk = rem >> 1;
  int n = nblk * 256 + threadIdx.x;
  const float* kb = known + ((size_t)b * Mm + half * 1024) * 3;
  for (int p = threadIdx.x; p < 1024; p += 256) {
    kx[p] = kb[3 * p]; ky[p] = kb[3 * p + 1]; kz[p] = kb[3 * p + 2];
  }
  __syncthreads();

  size_t ui = ((size_t)b * Nn + n) * 3;
  float ux = unknown[ui], uy = unknown[ui + 1], uz = unknown[ui + 2];
  float d0 = 1e30f, d1 = 1e30f, d2 = 1e30f;
  int i0 = 0, i1 = 0, i2 = 0;
  int gbase = half * 1024;

#define NN_STEP(xx, yy, zz, q)                                          \
  {                                                                     \
    float dx = ux - (xx), dy = uy - (yy), dz = uz - (zz);               \
    float dd = dx * dx + dy * dy + dz * dz;                             \
    if (__any(dd < d2)) {  /* wave-uniform skip of the insert chain */  \
      int jm = gbase + jb + (q);                                        \
      bool c0 = dd < d0, c1 = dd < d1, c2 = dd < d2;                    \
      d2 = c1 ? d1 : (c2 ? dd : d2); i2 = c1 ? i1 : (c2 ? jm : i2);     \
      d1 = c0 ? d0 : (c1 ? dd : d1); i1 = c0 ? i0 : (c1 ? jm : i1);     \
      d0 = c0 ? dd : d0;             i0 = c0 ? jm : i0;                 \
    }                                                                   \
  }

  for (int jb = 0; jb < 1024; jb += 4) {
    float4 xs = *(const float4*)&kx[jb];
    float4 ys = *(const float4*)&ky[jb];
    float4 zs = *(const float4*)&kz[jb];
    NN_STEP(xs.x, ys.x, zs.x, 0)
    NN_STEP(xs.y, ys.y, zs.y, 1)
    NN_STEP(xs.z, ys.z, zs.z, 2)
    NN_STEP(xs.w, ys.w, zs.w, 3)
  }
#undef NN_STEP

  size_t o = (((size_t)b * Nn + n) * 2 + half) * 3;
  pd[o] = d0; pd[o + 1] = d1; pd[o + 2] = d2;
  pi[o] = i0; pi[o + 1] = i1; pi[o + 2] = i2;
}

// ------------- merge the two sorted triples, compute weights -------------
__global__ __launch_bounds__(256) void nn_merge_k(const float* __restrict__ pd,
                                                  const int* __restrict__ pi,
                                                  int* __restrict__ idx3,
                                                  float* __restrict__ w3) {
  int t = blockIdx.x * 256 + threadIdx.x;  // flat b*N+n
  size_t o = (size_t)t * 6;
  float a0 = pd[o], a1 = pd[o + 1], a2 = pd[o + 2];
  float b0 = pd[o + 3], b1v = pd[o + 4], b2v = pd[o + 5];
  int A0 = pi[o], A1 = pi[o + 1], A2 = pi[o + 2];
  int B0 = pi[o + 3], B1 = pi[o + 4], B2 = pi[o + 5];
  bool ta = a0 <= b0;  // ties prefer list a (lower global index) = stable
  float m0 = ta ? a0 : b0; int j0 = ta ? A0 : B0;
  float na0 = ta ? a1 : a0, na1 = ta ? a2 : a1;
  int   nA0 = ta ? A1 : A0, nA1 = ta ? A2 : A1;
  float nb0 = ta ? b0 : b1v, nb1 = ta ? b1v : b2v;
  int   nB0 = ta ? B0 : B1,  nB1 = ta ? B1 : B2;
  ta = na0 <= nb0;
  float m1 = ta ? na0 : nb0; int j1 = ta ? nA0 : nB0;
  float ma0 = ta ? na1 : na0; int mA0 = ta ? nA1 : nA0;
  float mb0 = ta ? nb0 : nb1; int mB0 = ta ? nB0 : nB1;
  ta = ma0 <= mb0;
  float m2 = ta ? ma0 : mb0; int j2 = ta ? mA0 : mB0;

  float s0 = sqrtf(m0), s1 = sqrtf(m1), s2 = sqrtf(m2);
  float r0 = 1.f / (s0 + 1e-8f), r1 = 1.f / (s1 + 1e-8f), r2 = 1.f / (s2 + 1e-8f);
  float rs = 1.f / (r0 + r1 + r2);
  size_t ui = (size_t)t * 3;
  idx3[ui] = j0; idx3[ui + 1] = j1; idx3[ui + 2] = j2;
  w3[ui] = r0 * rs; w3[ui + 1] = r1 * rs; w3[ui + 2] = r2 * rs;
}

// ------------- fused: gather+concat -> MLP1 -> MLP2 -> out -------------
// block = 256 thr (4 waves), 64 cols x 256 rows. grid = 8*128 = 1024.
// LDS: Fs 48KB + Hs 32KB = 80KB -> 2 blocks/CU. Exactly 2 barriers per block.
__global__ __launch_bounds__(256) void fused_gemm_k(
    const float* __restrict__ uf, const float* __restrict__ kfT,
    const short* __restrict__ W1f, const float* __restrict__ b1,
    const short* __restrict__ W2f, const float* __restrict__ b2,
    const int* __restrict__ idx3, const float* __restrict__ w3,
    float* __restrict__ out) {
  __shared__ short Fs[KT1 * 4 * 64 * 8];  // B-frags of F  [kt][ntl][lane][j]
  __shared__ short Hs[KT2 * 4 * 64 * 8];  // B-frags of h  [ktg][ntl][lane][j]
  int bid = blockIdx.x;
  int b = bid >> 7, bt = bid & 127;  // n0 = bt*64
  int tid = threadIdx.x, lane = tid & 63, wv = tid >> 6;
  int quad = lane >> 4, col = lane & 15;

  // ---- Phase A: gather+concat F directly in B-frag layout
  {
    int n = bt * 64 + wv * 16 + col;
    size_t o3 = ((size_t)b * Nn + n) * 3;
    int g0 = idx3[o3], g1 = idx3[o3 + 1], g2 = idx3[o3 + 2];
    float w0 = w3[o3], w1 = w3[o3 + 1], w2 = w3[o3 + 2];
    const float* kfb = kfT + (size_t)b * Mm * C2;
#pragma unroll 2
    for (int kt = 0; kt < 8; ++kt) {  // interpolated region (C2 channels)
      int c0 = kt * 32 + quad * 8;
      float4 p0a = *(const float4*)&kfb[(size_t)g0 * C2 + c0];
      float4 p0b = *(const float4*)&kfb[(size_t)g0 * C2 + c0 + 4];
      float4 p1a = *(const float4*)&kfb[(size_t)g1 * C2 + c0];
      float4 p1b = *(const float4*)&kfb[(size_t)g1 * C2 + c0 + 4];
      float4 p2a = *(const float4*)&kfb[(size_t)g2 * C2 + c0];
      float4 p2b = *(const float4*)&kfb[(size_t)g2 * C2 + c0 + 4];
      bf16x8 f;
      f[0] = f2bf(w0 * p0a.x + w1 * p1a.x + w2 * p2a.x);
      f[1] = f2bf(w0 * p0a.y + w1 * p1a.y + w2 * p2a.y);
      f[2] = f2bf(w0 * p0a.z + w1 * p1a.z + w2 * p2a.z);
      f[3] = f2bf(w0 * p0a.w + w1 * p1a.w + w2 * p2a.w);
      f[4] = f2bf(w0 * p0b.x + w1 * p1b.x + w2 * p2b.x);
      f[5] = f2bf(w0 * p0b.y + w1 * p1b.y + w2 * p2b.y);
      f[6] = f2bf(w0 * p0b.z + w1 * p1b.z + w2 * p2b.z);
      f[7] = f2bf(w0 * p0b.w + w1 * p1b.w + w2 * p2b.w);
      *(bf16x8*)&Fs[((kt * 4 + wv) * 64 + lane) * 8] = f;
    }
#pragma unroll 2
    for (int kt = 8; kt < 12; ++kt) {  // unknow_feats region (C1 channels)
      int c1 = (kt - 8) * 32 + quad * 8;
      bf16x8 f;
#pragma unroll
      for (int j = 0; j < 8; ++j)
        f[j] = f2bf(uf[((size_t)b * C1 + c1 + j) * Nn + n]);
      *(bf16x8*)&Fs[((kt * 4 + wv) * 64 + lane) * 8] = f;
    }
  }
  __syncthreads();  // barrier 1

  // ---- K-loop 1: wave wv owns rows wv*64..+63 (4 row-tiles) x 4 col-tiles
  f32x4 acc[4][4];
#pragma unroll
  for (int r = 0; r < 4; ++r)
#pragma unroll
    for (int c = 0; c < 4; ++c) acc[r][c] = (f32x4){0.f, 0.f, 0.f, 0.f};

  for (int kt = 0; kt < KT1; ++kt) {
    bf16x8 Afr[4], Bfr[4];
#pragma unroll
    for (int r = 0; r < 4; ++r)
      Afr[r] = *(const bf16x8*)(W1f + ((size_t)(kt * RT + wv * 4 + r) * 64 + lane) * 8);
#pragma unroll
    for (int c = 0; c < 4; ++c)
      Bfr[c] = *(const bf16x8*)&Fs[((kt * 4 + c) * 64 + lane) * 8];
#pragma unroll
    for (int r = 0; r < 4; ++r)
#pragma unroll
      for (int c = 0; c < 4; ++c)
        acc[r][c] = __builtin_amdgcn_mfma_f32_16x16x32_bf16(Afr[r], Bfr[c], acc[r][c], 0, 0, 0);
  }

  // ---- Epilogue 1: bias+relu in D-layout, then register bpermute D->B-frag.
  // Target lane L, elem j of k-tile (wv*2+ktl): h[ch=ktl*32+(L>>4)*8+j][col]
  //   = reg (j&3) of acc[ktl*2 + (L>>5)][c] pulled from lane (2*(quad&1)+(j>>2))*16+col.
#pragma unroll
  for (int r = 0; r < 4; ++r) {
    f32x4 bq = *(const f32x4*)&b1[wv * 64 + r * 16 + quad * 4];
#pragma unroll
    for (int c = 0; c < 4; ++c)
#pragma unroll
      for (int reg = 0; reg < 4; ++reg)
        acc[r][c][reg] = fmaxf(acc[r][c][reg] + bq[reg], 0.f);
  }
  {
    int addr_lo = (((quad & 1) * 2) * 16 + col) * 4;  // src lane*4 for j<4
    bool hiSel = lane >= 32;
#pragma unroll
    for (int ktl = 0; ktl < 2; ++ktl)
#pragma unroll
      for (int c = 0; c < 4; ++c) {
        bf16x8 f;
#pragma unroll
        for (int j = 0; j < 8; ++j) {
          int addr = addr_lo + (j >> 2) * 64;
          int lo = __builtin_amdgcn_ds_bpermute(addr, __float_as_int(acc[ktl * 2][c][j & 3]));
          int hi = __builtin_amdgcn_ds_bpermute(addr, __float_as_int(acc[ktl * 2 + 1][c][j & 3]));
          f[j] = f2bf(__int_as_float(hiSel ? hi : lo));
        }
        *(bf16x8*)&Hs[(((wv * 2 + ktl) * 4 + c) * 64 + lane) * 8] = f;
      }
  }
  __syncthreads();  // barrier 2

  // ---- K-loop 2
  f32x4 acc2[4][4];
#pragma unroll
  for (int r = 0; r < 4; ++r)
#pragma unroll
    for (int c = 0; c < 4; ++c) acc2[r][c] = (f32x4){0.f, 0.f, 0.f, 0.f};

  for (int kt = 0; kt < KT2; ++kt) {
    bf16x8 Afr[4], Bfr[4];
#pragma unroll
    for (int r = 0; r < 4; ++r)
      Afr[r] = *(const bf16x8*)(W2f + ((size_t)(kt * RT + wv * 4 + r) * 64 + lane) * 8);
#pragma unroll
    for (int c = 0; c < 4; ++c)
      Bfr[c] = *(const bf16x8*)&Hs[((kt * 4 + c) * 64 + lane) * 8];
#pragma unroll
    for (int r = 0; r < 4; ++r)
#pragma unroll
      for (int c = 0; c < 4; ++c)
        acc2[r][c] = __builtin_amdgcn_mfma_f32_16x16x32_bf16(Afr[r], Bfr[c], acc2[r][c], 0, 0, 0);
  }

  // ---- Epilogue 2: bias+relu, store
#pragma unroll
  for (int r = 0; r < 4; ++r) {
    f32x4 bq = *(const f32x4*)&b2[wv * 64 + r * 16 + quad * 4];
#pragma unroll
    for (int c = 0; c < 4; ++c)
#pragma unroll
      for (int reg = 0; reg < 4; ++reg) {
        int rowg = wv * 64 + r * 16 + quad * 4 + reg;
        int n = bt * 64 + c * 16 + col;
        out[((size_t)b * Hh + rowg) * Nn + n] = fmaxf(acc2[r][c][reg] + bq[reg], 0.f);
      }
  }
}

extern "C" void kernel_launch(void* const* d_in, const int* in_sizes, int n_in,
                              void* d_out, int out_size, void* d_ws, size_t ws_size,
                              hipStream_t stream) {
  const float* unknown = (const float*)d_in[0];
  const float* known   = (const float*)d_in[1];
  const float* uf      = (const float*)d_in[2];
  const float* kf      = (const float*)d_in[3];
  const float* W1      = (const float*)d_in[4];
  const float* b1      = (const float*)d_in[5];
  const float* W2      = (const float*)d_in[6];
  const float* b2      = (const float*)d_in[7];
  float* out = (float*)d_out;

  // ws layout (~22 MB)
  char* p = (char*)d_ws;
  float* kfT = (float*)p;  p += (size_t)Bb * Mm * C2 * 4;
  int* idx3  = (int*)p;    p += (size_t)Bb * Nn * 3 * 4;
  float* w3  = (float*)p;  p += (size_t)Bb * Nn * 3 * 4;
  short* W1f = (short*)p;  p += (size_t)KT1 * RT * 64 * 8 * 2;
  short* W2f = (short*)p;  p += (size_t)KT2 * RT * 64 * 8 * 2;
  float* pd  = (float*)p;  p += (size_t)Bb * Nn * 2 * 3 * 4;
  int* pi    = (int*)p;    p += (size_t)Bb * Nn * 2 * 3 * 4;

  transpose_k<<<dim3(Mm / 32, C2 / 32, Bb), dim3(32, 8), 0, stream>>>(kf, kfT, C2, Mm);
  prep_w_k<<<dim3((KT1 * RT * 64 + KT2 * RT * 64) / 256), dim3(256), 0, stream>>>(W1, W2, W1f, W2f);
  nn_half_k<<<dim3(Bb * 64), dim3(256), 0, stream>>>(unknown, known, pd, pi);
  nn_merge_k<<<dim3(Bb * Nn / 256), dim3(256), 0, stream>>>(pd, pi, idx3, w3);
  fused_gemm_k<<<dim3(Bb * (Nn / 64)), dim3(256), 0, stream>>>(
      uf, kfT, W1f, b1, W2f, b2, idx3, w3, out);
}

// Round 4
// 223.550 us; speedup vs baseline: 3.7742x; 1.0784x over previous
//
#include <hip/hip_runtime.h>

using bf16x8 = __attribute__((ext_vector_type(8))) short;
using f32x4  = __attribute__((ext_vector_type(4))) float;

constexpr int Bb = 8, Nn = 8192, Mm = 2048, C1 = 128, C2 = 256, Hh = 256, K1 = 384;
constexpr int KT1 = K1 / 32;   // 12 k-tiles for GEMM1
constexpr int KT2 = Hh / 32;   // 8 k-tiles for GEMM2
constexpr int RT = Hh / 16;    // 16 row-tiles
constexpr int NQ = 4;          // candidate-set split for three_nn
constexpr int MQ = Mm / NQ;    // 512 candidates per quarter

__device__ __forceinline__ short f2bf(float x) {  // RNE float->bf16
  union { float f; unsigned u; } v; v.f = x;
  unsigned r = v.u + 0x7fff + ((v.u >> 16) & 1);
  return (short)(r >> 16);
}

// stable 2-list merge of sorted triples; ties prefer list a (lower global idx)
__device__ __forceinline__ void merge3(float a0, float a1, float a2, int A0, int A1, int A2,
                                       float b0, float b1, float b2, int B0, int B1, int B2,
                                       float& m0, float& m1, float& m2,
                                       int& j0, int& j1, int& j2) {
  bool ta = a0 <= b0;
  m0 = ta ? a0 : b0; j0 = ta ? A0 : B0;
  float na0 = ta ? a1 : a0, na1 = ta ? a2 : a1;
  int   nA0 = ta ? A1 : A0, nA1 = ta ? A2 : A1;
  float nb0 = ta ? b0 : b1, nb1 = ta ? b1 : b2;
  int   nB0 = ta ? B0 : B1, nB1 = ta ? B1 : B2;
  ta = na0 <= nb0;
  m1 = ta ? na0 : nb0; j1 = ta ? nA0 : nB0;
  float ma0 = ta ? na1 : na0; int mA0 = ta ? nA1 : nA0;
  float mb0 = ta ? nb0 : nb1; int mB0 = ta ? nB0 : nB1;
  ta = ma0 <= mb0;
  m2 = ta ? ma0 : mb0; j2 = ta ? mA0 : mB0;
}

// ------------- combined prep: kf transpose (blocks 0..4095) + W frag prep -------------
// transpose: (B,C2,Mm) -> kfT (B,Mm,C2).  W-prep: A-frag planes, lane holds
// A[m=lane&15][k0..k0+7], k0=(lane>>4)*8; plane idx ((kt*RT+rt)*64+lane)*8+j.
__global__ __launch_bounds__(256) void prep_all_k(const float* __restrict__ kf,
                                                  float* __restrict__ kfT,
                                                  const float* __restrict__ W1,
                                                  const float* __restrict__ W2,
                                                  short* __restrict__ W1f,
                                                  short* __restrict__ W2f) {
  __shared__ float tile[32][33];
  int bid = blockIdx.x, tid = threadIdx.x;
  if (bid < 4096) {  // transpose role: grid (cx 64, ry 8, z 8) flattened
    int cx = bid & 63, ry = (bid >> 6) & 7, z = bid >> 9;
    const int R = C2, C = Mm;
    const float* src = kf + (size_t)z * R * C;
    float* dst = kfT + (size_t)z * R * C;
    int c0 = cx * 32, r0 = ry * 32;
    int tx = tid & 31, ty = tid >> 5;
#pragma unroll
    for (int rr = ty; rr < 32; rr += 8) tile[rr][tx] = src[(size_t)(r0 + rr) * C + c0 + tx];
    __syncthreads();
#pragma unroll
    for (int cc = ty; cc < 32; cc += 8) dst[(size_t)(c0 + cc) * R + r0 + tx] = tile[tx][cc];
    return;
  }
  int id = (bid - 4096) * 256 + tid;
  const int n1 = KT1 * RT * 64;
  const int n2 = KT2 * RT * 64;
  if (id < n1) {
    int lane = id & 63, t = id >> 6;
    int kt = t / RT, rt = t % RT;
    int m = rt * 16 + (lane & 15), k0 = kt * 32 + (lane >> 4) * 8;
    bf16x8 f;
#pragma unroll
    for (int j = 0; j < 8; ++j) f[j] = f2bf(W1[(size_t)m * K1 + k0 + j]);
    *(bf16x8*)(W1f + (size_t)id * 8) = f;
  } else if (id < n1 + n2) {
    int id2 = id - n1;
    int lane = id2 & 63, t = id2 >> 6;
    int kt = t / RT, rt = t % RT;
    int m = rt * 16 + (lane & 15), k0 = kt * 32 + (lane >> 4) * 8;
    bf16x8 f;
#pragma unroll
    for (int j = 0; j < 8; ++j) f[j] = f2bf(W2[(size_t)m * Hh + k0 + j]);
    *(bf16x8*)(W2f + (size_t)id2 * 8) = f;
  }
}

// ------------- three_nn over a quarter of the candidate set -------------
// grid: b(8) x nblk(32) x q(4) = 1024 blocks of 256 -> 16 waves/CU.
__global__ __launch_bounds__(256) void nn_quarter_k(const float* __restrict__ unknown,
                                                    const float* __restrict__ known,
                                                    float* __restrict__ pd,
                                                    int* __restrict__ pi) {
  __shared__ float kx[MQ], ky[MQ], kz[MQ];
  int bid = blockIdx.x;
  int b = bid >> 7, rem = bid & 127;
  int q = rem & 3, nblk = rem >> 2;
  int n = nblk * 256 + threadIdx.x;
  const float* kb = known + ((size_t)b * Mm + q * MQ) * 3;
  for (int p = threadIdx.x; p < MQ; p += 256) {
    kx[p] = kb[3 * p]; ky[p] = kb[3 * p + 1]; kz[p] = kb[3 * p + 2];
  }
  __syncthreads();

  size_t ui = ((size_t)b * Nn + n) * 3;
  float ux = unknown[ui], uy = unknown[ui + 1], uz = unknown[ui + 2];
  float d0 = 1e30f, d1 = 1e30f, d2 = 1e30f;
  int i0 = 0, i1 = 0, i2 = 0;
  int gbase = q * MQ;

#define NN_STEP(xx, yy, zz, qq)                                         \
  {                                                                     \
    float dx = ux - (xx), dy = uy - (yy), dz = uz - (zz);               \
    float dd = dx * dx + dy * dy + dz * dz;                             \
    if (__any(dd < d2)) {  /* wave-uniform skip of the insert chain */  \
      int jm = gbase + jb + (qq);                                       \
      bool c0 = dd < d0, c1 = dd < d1, c2 = dd < d2;                    \
      d2 = c1 ? d1 : (c2 ? dd : d2); i2 = c1 ? i1 : (c2 ? jm : i2);     \
      d1 = c0 ? d0 : (c1 ? dd : d1); i1 = c0 ? i0 : (c1 ? jm : i1);     \
      d0 = c0 ? dd : d0;             i0 = c0 ? jm : i0;                 \
    }                                                                   \
  }

  for (int jb = 0; jb < MQ; jb += 4) {
    float4 xs = *(const float4*)&kx[jb];
    float4 ys = *(const float4*)&ky[jb];
    float4 zs = *(const float4*)&kz[jb];
    NN_STEP(xs.x, ys.x, zs.x, 0)
    NN_STEP(xs.y, ys.y, zs.y, 1)
    NN_STEP(xs.z, ys.z, zs.z, 2)
    NN_STEP(xs.w, ys.w, zs.w, 3)
  }
#undef NN_STEP

  size_t o = (((size_t)b * Nn + n) * NQ + q) * 3;
  pd[o] = d0; pd[o + 1] = d1; pd[o + 2] = d2;
  pi[o] = i0; pi[o + 1] = i1; pi[o + 2] = i2;
}

// ------------- fused: 4-way merge -> gather+concat -> MLP1 -> MLP2 -> out -------------
// block = 256 thr (4 waves), 64 cols x 256 rows. grid = 8*128 = 1024.
// LDS: Fs 48KB + Hs 32KB = 80KB -> 2 blocks/CU. Exactly 2 barriers per block.
__global__ __launch_bounds__(256) void fused_gemm_k(
    const float* __restrict__ uf, const float* __restrict__ kfT,
    const short* __restrict__ W1f, const float* __restrict__ b1,
    const short* __restrict__ W2f, const float* __restrict__ b2,
    const float* __restrict__ pd, const int* __restrict__ pi,
    float* __restrict__ out) {
  __shared__ short Fs[KT1 * 4 * 64 * 8];  // B-frags of F  [kt][ntl][lane][j]
  __shared__ short Hs[KT2 * 4 * 64 * 8];  // B-frags of h  [ktg][ntl][lane][j]
  int bid = blockIdx.x;
  int b = bid >> 7, bt = bid & 127;  // n0 = bt*64
  int tid = threadIdx.x, lane = tid & 63, wv = tid >> 6;
  int quad = lane >> 4, col = lane & 15;

  // ---- Phase A: in-register 4-way NN merge, then gather+concat F in B-frag layout
  {
    int n = bt * 64 + wv * 16 + col;
    size_t pbase = (size_t)(b * Nn + n) * (NQ * 3);
    float4 da = *(const float4*)&pd[pbase];
    float4 db = *(const float4*)&pd[pbase + 4];
    float4 dc = *(const float4*)&pd[pbase + 8];
    int4 ia = *(const int4*)&pi[pbase];
    int4 ib = *(const int4*)&pi[pbase + 4];
    int4 ic = *(const int4*)&pi[pbase + 8];
    float t0, t1, t2, u0, u1, u2, m0, m1, m2;
    int T0, T1, T2, U0, U1, U2, g0, g1, g2;
    merge3(da.x, da.y, da.z, ia.x, ia.y, ia.z,
           da.w, db.x, db.y, ia.w, ib.x, ib.y, t0, t1, t2, T0, T1, T2);
    merge3(db.z, db.w, dc.x, ib.z, ib.w, ic.x,
           dc.y, dc.z, dc.w, ic.y, ic.z, ic.w, u0, u1, u2, U0, U1, U2);
    merge3(t0, t1, t2, T0, T1, T2, u0, u1, u2, U0, U1, U2,
           m0, m1, m2, g0, g1, g2);
    float s0 = sqrtf(m0), s1 = sqrtf(m1), s2 = sqrtf(m2);
    float r0 = 1.f / (s0 + 1e-8f), r1 = 1.f / (s1 + 1e-8f), r2 = 1.f / (s2 + 1e-8f);
    float rs = 1.f / (r0 + r1 + r2);
    float w0 = r0 * rs, w1 = r1 * rs, w2 = r2 * rs;

    const float* kfb = kfT + (size_t)b * Mm * C2;
#pragma unroll 2
    for (int kt = 0; kt < 8; ++kt) {  // interpolated region (C2 channels)
      int c0 = kt * 32 + quad * 8;
      float4 p0a = *(const float4*)&kfb[(size_t)g0 * C2 + c0];
      float4 p0b = *(const float4*)&kfb[(size_t)g0 * C2 + c0 + 4];
      float4 p1a = *(const float4*)&kfb[(size_t)g1 * C2 + c0];
      float4 p1b = *(const float4*)&kfb[(size_t)g1 * C2 + c0 + 4];
      float4 p2a = *(const float4*)&kfb[(size_t)g2 * C2 + c0];
      float4 p2b = *(const float4*)&kfb[(size_t)g2 * C2 + c0 + 4];
      bf16x8 f;
      f[0] = f2bf(w0 * p0a.x + w1 * p1a.x + w2 * p2a.x);
      f[1] = f2bf(w0 * p0a.y + w1 * p1a.y + w2 * p2a.y);
      f[2] = f2bf(w0 * p0a.z + w1 * p1a.z + w2 * p2a.z);
      f[3] = f2bf(w0 * p0a.w + w1 * p1a.w + w2 * p2a.w);
      f[4] = f2bf(w0 * p0b.x + w1 * p1b.x + w2 * p2b.x);
      f[5] = f2bf(w0 * p0b.y + w1 * p1b.y + w2 * p2b.y);
      f[6] = f2bf(w0 * p0b.z + w1 * p1b.z + w2 * p2b.z);
      f[7] = f2bf(w0 * p0b.w + w1 * p1b.w + w2 * p2b.w);
      *(bf16x8*)&Fs[((kt * 4 + wv) * 64 + lane) * 8] = f;
    }
#pragma unroll 2
    for (int kt = 8; kt < 12; ++kt) {  // unknow_feats region (C1 channels)
      int c1 = (kt - 8) * 32 + quad * 8;
      bf16x8 f;
#pragma unroll
      for (int j = 0; j < 8; ++j)
        f[j] = f2bf(uf[((size_t)b * C1 + c1 + j) * Nn + n]);
      *(bf16x8*)&Fs[((kt * 4 + wv) * 64 + lane) * 8] = f;
    }
  }
  __syncthreads();  // barrier 1

  // ---- K-loop 1: wave wv owns rows wv*64..+63 (4 row-tiles) x 4 col-tiles
  f32x4 acc[4][4];
#pragma unroll
  for (int r = 0; r < 4; ++r)
#pragma unroll
    for (int c = 0; c < 4; ++c) acc[r][c] = (f32x4){0.f, 0.f, 0.f, 0.f};

  for (int kt = 0; kt < KT1; ++kt) {
    bf16x8 Afr[4], Bfr[4];
#pragma unroll
    for (int r = 0; r < 4; ++r)
      Afr[r] = *(const bf16x8*)(W1f + ((size_t)(kt * RT + wv * 4 + r) * 64 + lane) * 8);
#pragma unroll
    for (int c = 0; c < 4; ++c)
      Bfr[c] = *(const bf16x8*)&Fs[((kt * 4 + c) * 64 + lane) * 8];
#pragma unroll
    for (int r = 0; r < 4; ++r)
#pragma unroll
      for (int c = 0; c < 4; ++c)
        acc[r][c] = __builtin_amdgcn_mfma_f32_16x16x32_bf16(Afr[r], Bfr[c], acc[r][c], 0, 0, 0);
  }

  // ---- Epilogue 1: bias+relu in D-layout, then register bpermute D->B-frag.
#pragma unroll
  for (int r = 0; r < 4; ++r) {
    f32x4 bq = *(const f32x4*)&b1[wv * 64 + r * 16 + quad * 4];
#pragma unroll
    for (int c = 0; c < 4; ++c)
#pragma unroll
      for (int reg = 0; reg < 4; ++reg)
        acc[r][c][reg] = fmaxf(acc[r][c][reg] + bq[reg], 0.f);
  }
  {
    int addr_lo = (((quad & 1) * 2) * 16 + col) * 4;  // src lane*4 for j<4
    bool hiSel = lane >= 32;
#pragma unroll
    for (int ktl = 0; ktl < 2; ++ktl)
#pragma unroll
      for (int c = 0; c < 4; ++c) {
        bf16x8 f;
#pragma unroll
        for (int j = 0; j < 8; ++j) {
          int addr = addr_lo + (j >> 2) * 64;
          int lo = __builtin_amdgcn_ds_bpermute(addr, __float_as_int(acc[ktl * 2][c][j & 3]));
          int hi = __builtin_amdgcn_ds_bpermute(addr, __float_as_int(acc[ktl * 2 + 1][c][j & 3]));
          f[j] = f2bf(__int_as_float(hiSel ? hi : lo));
        }
        *(bf16x8*)&Hs[(((wv * 2 + ktl) * 4 + c) * 64 + lane) * 8] = f;
      }
  }
  __syncthreads();  // barrier 2

  // ---- K-loop 2
  f32x4 acc2[4][4];
#pragma unroll
  for (int r = 0; r < 4; ++r)
#pragma unroll
    for (int c = 0; c < 4; ++c) acc2[r][c] = (f32x4){0.f, 0.f, 0.f, 0.f};

  for (int kt = 0; kt < KT2; ++kt) {
    bf16x8 Afr[4], Bfr[4];
#pragma unroll
    for (int r = 0; r < 4; ++r)
      Afr[r] = *(const bf16x8*)(W2f + ((size_t)(kt * RT + wv * 4 + r) * 64 + lane) * 8);
#pragma unroll
    for (int c = 0; c < 4; ++c)
      Bfr[c] = *(const bf16x8*)&Hs[((kt * 4 + c) * 64 + lane) * 8];
#pragma unroll
    for (int r = 0; r < 4; ++r)
#pragma unroll
      for (int c = 0; c < 4; ++c)
        acc2[r][c] = __builtin_amdgcn_mfma_f32_16x16x32_bf16(Afr[r], Bfr[c], acc2[r][c], 0, 0, 0);
  }

  // ---- Epilogue 2: bias+relu, store
#pragma unroll
  for (int r = 0; r < 4; ++r) {
    f32x4 bq = *(const f32x4*)&b2[wv * 64 + r * 16 + quad * 4];
#pragma unroll
    for (int c = 0; c < 4; ++c)
#pragma unroll
      for (int reg = 0; reg < 4; ++reg) {
        int rowg = wv * 64 + r * 16 + quad * 4 + reg;
        int n = bt * 64 + c * 16 + col;
        out[((size_t)b * Hh + rowg) * Nn + n] = fmaxf(acc2[r][c][reg] + bq[reg], 0.f);
      }
  }
}

extern "C" void kernel_launch(void* const* d_in, const int* in_sizes, int n_in,
                              void* d_out, int out_size, void* d_ws, size_t ws_size,
                              hipStream_t stream) {
  const float* unknown = (const float*)d_in[0];
  const float* known   = (const float*)d_in[1];
  const float* uf      = (const float*)d_in[2];
  const float* kf      = (const float*)d_in[3];
  const float* W1      = (const float*)d_in[4];
  const float* b1      = (const float*)d_in[5];
  const float* W2      = (const float*)d_in[6];
  const float* b2      = (const float*)d_in[7];
  float* out = (float*)d_out;

  // ws layout (~24 MB)
  char* p = (char*)d_ws;
  float* kfT = (float*)p;  p += (size_t)Bb * Mm * C2 * 4;
  short* W1f = (short*)p;  p += (size_t)KT1 * RT * 64 * 8 * 2;
  short* W2f = (short*)p;  p += (size_t)KT2 * RT * 64 * 8 * 2;
  float* pd  = (float*)p;  p += (size_t)Bb * Nn * NQ * 3 * 4;
  int* pi    = (int*)p;    p += (size_t)Bb * Nn * NQ * 3 * 4;

  const int prep_blocks = 4096 + (KT1 * RT * 64 + KT2 * RT * 64 + 255) / 256;
  prep_all_k<<<dim3(prep_blocks), dim3(256), 0, stream>>>(kf, kfT, W1, W2, W1f, W2f);
  nn_quarter_k<<<dim3(Bb * 32 * NQ), dim3(256), 0, stream>>>(unknown, known, pd, pi);
  fused_gemm_k<<<dim3(Bb * (Nn / 64)), dim3(256), 0, stream>>>(
      uf, kfT, W1f, b1, W2f, b2, pd, pi, out);
}